// Round 3
// baseline (97.480 us; speedup 1.0000x reference)
//
#include <hip/hip_runtime.h>
#include <stdint.h>

#define NPRED   16384
#define NGT     128
#define KSEL    64
#define CAP     384
#define G       4          // gts per block, one wave each
#define THREADS 256
#define CHUNK   2048
#define NCHUNK  (NPRED / CHUNK)
#define T0      0.055f     // initial radius (E[C] ~ 155 for uniform data)

typedef unsigned long long u64;

// Outputs (float32, concatenated): ious[16*128*64], mask[...], k_idx[...]
#define OUT_IOUS 0
#define OUT_MASK (16 * NGT * KSEL)
#define OUT_KIDX (2 * 16 * NGT * KSEL)

// numpy-exact pairwise sum of 64 per-lane values (n=64: 8 strided partials,
// then ((r0+r1)+(r2+r3)) + ((r4+r5)+(r6+r7))). All lanes return the sum.
__device__ __forceinline__ float npsum64(float v, int lane) {
    const int j = lane & 7;
    float r = __shfl(v, j, 64);                       // a[j]
    #pragma unroll
    for (int k = 1; k < 8; ++k)
        r = __fadd_rn(r, __shfl(v, j + 8 * k, 64));   // += a[j+8k], in order
    const float r0 = __shfl(r, 0, 64), r1 = __shfl(r, 1, 64),
                r2 = __shfl(r, 2, 64), r3 = __shfl(r, 3, 64),
                r4 = __shfl(r, 4, 64), r5 = __shfl(r, 5, 64),
                r6 = __shfl(r, 6, 64), r7 = __shfl(r, 7, 64);
    return __fadd_rn(__fadd_rn(__fadd_rn(r0, r1), __fadd_rn(r2, r3)),
                     __fadd_rn(__fadd_rn(r4, r5), __fadd_rn(r6, r7)));
}

__global__ __launch_bounds__(THREADS) void atss_kernel(
    const float* __restrict__ pred,  // [16][16384][4] cxcywh
    const float* __restrict__ gt,    // [16][128][4]  cxcywh
    float* __restrict__ out)
{
    __shared__ __align__(16) float2 s_xy[CHUNK];   // staged (cx,cy) chunk
    __shared__ u64 cand[G][CAP];
    __shared__ u64 topk[G][KSEL];
    __shared__ int s_cnt[G];

    const int tid  = threadIdx.x;
    const int w    = tid >> 6;        // wave id = gt slot in this block
    const int lane = tid & 63;
    const int b    = blockIdx.x >> 5;         // 32 groups per batch
    const int g    = (blockIdx.x & 31) * G + w;
    const int task = b * NGT + g;

    const float* gtp = gt + task * 4;
    const float gcx = gtp[0], gcy = gtp[1], gw = gtp[2], gh = gtp[3];
    const float*  pb = pred + (size_t)b * NPRED * 4;
    const float4* p4 = reinterpret_cast<const float4*>(pb);
    const float2* pc = reinterpret_cast<const float2*>(pb);  // pc[2i] = (cx,cy)

    if (lane == 0) s_cnt[w] = 0;   // own wave's counter; in-order LDS pipe

    // ---- Phase 1: staged cooperative scan, one wave per gt ----
    float Tf = T0;
    float T2 = Tf * Tf;

    float4 stg[8];
    {   // prologue: load chunk 0 into regs
        const float4* src = p4 + tid;
        #pragma unroll
        for (int k = 0; k < 8; ++k) stg[k] = src[k * 256];
    }

    for (int c = 0; c < NCHUNK; ++c) {
        __syncthreads();                    // staging buffer free
        #pragma unroll
        for (int k = 0; k < 8; ++k)
            s_xy[tid + k * 256] = make_float2(stg[k].x, stg[k].y);
        __syncthreads();                    // staging ready
        if (c + 1 < NCHUNK) {               // prefetch next chunk (in flight during scan)
            const float4* src = p4 + (c + 1) * CHUNK + tid;
            #pragma unroll
            for (int k = 0; k < 8; ++k) stg[k] = src[k * 256];
        }
        const int cb = c * CHUNK;
        #pragma unroll 4
        for (int j = 0; j < CHUNK / 128; ++j) {
            const float4 t = *reinterpret_cast<const float4*>(&s_xy[j * 128 + lane * 2]);
            const int i0 = cb + j * 128 + lane * 2;
            {
                float dx = __fsub_rn(gcx, t.x), dy = __fsub_rn(gcy, t.y);
                if (fmaf(dx, dx, dy * dy) < T2) {
                    float d = __fsqrt_rn(__fadd_rn(__fmul_rn(dx, dx), __fmul_rn(dy, dy)));
                    int pos = atomicAdd(&s_cnt[w], 1);
                    if (pos < CAP)
                        cand[w][pos] = ((u64)__float_as_uint(d) << 32) | (unsigned)i0;
                }
            }
            {
                float dx = __fsub_rn(gcx, t.z), dy = __fsub_rn(gcy, t.w);
                if (fmaf(dx, dx, dy * dy) < T2) {
                    float d = __fsqrt_rn(__fadd_rn(__fmul_rn(dx, dx), __fmul_rn(dy, dy)));
                    int pos = atomicAdd(&s_cnt[w], 1);
                    if (pos < CAP)
                        cand[w][pos] = ((u64)__float_as_uint(d) << 32) | (unsigned)(i0 + 1);
                }
            }
        }
    }
    // NO block barriers below this point: everything is wave-local.

    // ---- Phase 1b: per-wave retry for under/overflow (rare: edge/corner gts) ----
    int C = s_cnt[w];
    for (int attempt = 0; attempt < 8 && (C < KSEL || C > CAP); ++attempt) {
        Tf = (C < KSEL) ? Tf * 2.0f : Tf * 0.5f;
        T2 = Tf * Tf;
        if (lane == 0) s_cnt[w] = 0;
        __builtin_amdgcn_wave_barrier();
        for (int i = lane; i < NPRED; i += 64) {      // slow path: global reads
            const float2 p = pc[i * 2];
            float dx = __fsub_rn(gcx, p.x), dy = __fsub_rn(gcy, p.y);
            if (fmaf(dx, dx, dy * dy) < T2) {
                float d = __fsqrt_rn(__fadd_rn(__fmul_rn(dx, dx), __fmul_rn(dy, dy)));
                int pos = atomicAdd(&s_cnt[w], 1);
                if (pos < CAP)
                    cand[w][pos] = ((u64)__float_as_uint(d) << 32) | (unsigned)i;
            }
        }
        __builtin_amdgcn_wave_barrier();
        C = s_cnt[w];
    }
    if (C > CAP) C = CAP;   // safety only

    // ---- Phase 2: per-wave O(C^2) rank selection (unique keys -> unique ranks) ----
    asm volatile("s_waitcnt lgkmcnt(0)" ::: "memory");
    __builtin_amdgcn_wave_barrier();
    for (int ci = lane; ci < C; ci += 64) {
        const u64 key = cand[w][ci];
        int r = 0;
        for (int j = 0; j < C; ++j)
            r += (cand[w][j] < key) ? 1 : 0;          // broadcast LDS read
        if (r < KSEL) topk[w][r] = key;
    }
    asm volatile("s_waitcnt lgkmcnt(0)" ::: "memory");
    __builtin_amdgcn_wave_barrier();

    // ---- Phase 3: epilogue, one lane per selected box (numpy-exact f32) ----
    const u64 key = topk[w][lane];
    const int idx = (int)(key & (u64)(NPRED - 1));    // low bits; mask = OOB insurance

    const float gx1 = __fsub_rn(gcx, __fmul_rn(0.5f, gw));
    const float gy1 = __fsub_rn(gcy, __fmul_rn(0.5f, gh));
    const float gx2 = __fadd_rn(gcx, __fmul_rn(0.5f, gw));
    const float gy2 = __fadd_rn(gcy, __fmul_rn(0.5f, gh));

    const float4 kb = *reinterpret_cast<const float4*>(pb + (size_t)idx * 4);
    const float kcx = kb.x, kcy = kb.y;
    float kx1 = __fsub_rn(kb.x, __fmul_rn(0.5f, kb.z));
    float ky1 = __fsub_rn(kb.y, __fmul_rn(0.5f, kb.w));
    float kx2 = __fadd_rn(kb.x, __fmul_rn(0.5f, kb.z));
    float ky2 = __fadd_rn(kb.y, __fmul_rn(0.5f, kb.w));
    float ltx = fmaxf(gx1, kx1), lty = fmaxf(gy1, ky1);
    float rbx = fminf(gx2, kx2), rby = fminf(gy2, ky2);
    float wx = fmaxf(__fsub_rn(rbx, ltx), 0.0f);
    float wy = fmaxf(__fsub_rn(rby, lty), 0.0f);
    float inter = __fmul_rn(wx, wy);
    float ag = __fmul_rn(__fsub_rn(gx2, gx1), __fsub_rn(gy2, gy1));
    float ak = __fmul_rn(__fsub_rn(kx2, kx1), __fsub_rn(ky2, ky1));
    float uni = __fsub_rn(__fadd_rn(ag, ak), inter);
    const float iou = __fdiv_rn(inter, uni);

    const float mean = __fdiv_rn(npsum64(iou, lane), 64.0f);
    const float dd   = __fsub_rn(iou, mean);
    const float var  = __fdiv_rn(npsum64(__fmul_rn(dd, dd), lane), 63.0f);
    const float thr  = __fadd_rn(mean, __fsqrt_rn(var));

    const bool inside = (gx1 <= kcx) && (kcx <= gx2) && (gy1 <= kcy) && (kcy <= gy2);
    const bool m = (iou >= thr) && inside;

    const int o = task * KSEL + lane;
    out[OUT_IOUS + o] = iou;
    out[OUT_MASK + o] = m ? 1.0f : 0.0f;
    out[OUT_KIDX + o] = (float)idx;
}

extern "C" void kernel_launch(void* const* d_in, const int* in_sizes, int n_in,
                              void* d_out, int out_size, void* d_ws, size_t ws_size,
                              hipStream_t stream) {
    const float* pred = (const float*)d_in[0];  // (16,16384,4) f32
    const float* gtb  = (const float*)d_in[1];  // (16,128,4)   f32
    float* out = (float*)d_out;
    dim3 grid(16 * (NGT / G));   // 512 blocks: (batch, gt-group)
    dim3 block(THREADS);
    hipLaunchKernelGGL(atss_kernel, grid, block, 0, stream, pred, gtb, out);
}

// Round 4
// 40.016 us; speedup vs baseline: 2.4360x; 2.4360x over previous
//
#include <hip/hip_runtime.h>
#include <stdint.h>

#define NPRED   16384
#define NGT     128
#define KSEL    64
#define CAP     384
#define THREADS 256
#define T0      0.055f     // initial radius (E[C] ~ 155 for uniform data)
#define BCAP    128        // per-cell capacity (mean 64, 8 sigma)
#define NCELL   256        // 16x16 grid per batch

typedef unsigned long long u64;

// Outputs (float32, concatenated): ious[16*128*64], mask[...], k_idx[...]
#define OUT_IOUS 0
#define OUT_MASK (16 * NGT * KSEL)
#define OUT_KIDX (2 * 16 * NGT * KSEL)

// ws layout (bytes)
#define WS_COUNTS 0
#define WS_BIDX   16384
#define WS_BXY    (16384 + 16 * NCELL * BCAP * 4)
#define WS_NEEDED (16384 + 16 * NCELL * BCAP * 4 + 16 * NCELL * BCAP * 8)

// numpy-exact pairwise sum of 64 per-lane values (n=64: 8 strided partials,
// then ((r0+r1)+(r2+r3)) + ((r4+r5)+(r6+r7))). All lanes return the sum.
// Validated bit-exact (absmax=0) in prior rounds.
__device__ __forceinline__ float npsum64(float v, int lane) {
    const int j = lane & 7;
    float r = __shfl(v, j, 64);                       // a[j]
    #pragma unroll
    for (int k = 1; k < 8; ++k)
        r = __fadd_rn(r, __shfl(v, j + 8 * k, 64));   // += a[j+8k], in order
    const float r0 = __shfl(r, 0, 64), r1 = __shfl(r, 1, 64),
                r2 = __shfl(r, 2, 64), r3 = __shfl(r, 3, 64),
                r4 = __shfl(r, 4, 64), r5 = __shfl(r, 5, 64),
                r6 = __shfl(r, 6, 64), r7 = __shfl(r, 7, 64);
    return __fadd_rn(__fadd_rn(__fadd_rn(r0, r1), __fadd_rn(r2, r3)),
                     __fadd_rn(__fadd_rn(r4, r5), __fadd_rn(r6, r7)));
}

// Shared epilogue: IoU, mean+std(ddof=1) threshold, mask — numpy-exact f32.
// Executed by wave 0 only (tid < 64). Keys in topk[0..63].
__device__ __forceinline__ void epilogue(
    const u64* topk, const float* pb, int task, int lane,
    float gcx, float gcy, float gw, float gh, float* out)
{
    const u64 key = topk[lane];
    const int idx = (int)(key & (u64)(NPRED - 1));

    const float gx1 = __fsub_rn(gcx, __fmul_rn(0.5f, gw));
    const float gy1 = __fsub_rn(gcy, __fmul_rn(0.5f, gh));
    const float gx2 = __fadd_rn(gcx, __fmul_rn(0.5f, gw));
    const float gy2 = __fadd_rn(gcy, __fmul_rn(0.5f, gh));

    const float4 kb = *reinterpret_cast<const float4*>(pb + (size_t)idx * 4);
    const float kcx = kb.x, kcy = kb.y;
    float kx1 = __fsub_rn(kb.x, __fmul_rn(0.5f, kb.z));
    float ky1 = __fsub_rn(kb.y, __fmul_rn(0.5f, kb.w));
    float kx2 = __fadd_rn(kb.x, __fmul_rn(0.5f, kb.z));
    float ky2 = __fadd_rn(kb.y, __fmul_rn(0.5f, kb.w));
    float ltx = fmaxf(gx1, kx1), lty = fmaxf(gy1, ky1);
    float rbx = fminf(gx2, kx2), rby = fminf(gy2, ky2);
    float wx = fmaxf(__fsub_rn(rbx, ltx), 0.0f);
    float wy = fmaxf(__fsub_rn(rby, lty), 0.0f);
    float inter = __fmul_rn(wx, wy);
    float ag = __fmul_rn(__fsub_rn(gx2, gx1), __fsub_rn(gy2, gy1));
    float ak = __fmul_rn(__fsub_rn(kx2, kx1), __fsub_rn(ky2, ky1));
    float uni = __fsub_rn(__fadd_rn(ag, ak), inter);
    const float iou = __fdiv_rn(inter, uni);

    const float mean = __fdiv_rn(npsum64(iou, lane), 64.0f);
    const float dd   = __fsub_rn(iou, mean);
    const float var  = __fdiv_rn(npsum64(__fmul_rn(dd, dd), lane), 63.0f);
    const float thr  = __fadd_rn(mean, __fsqrt_rn(var));

    const bool inside = (gx1 <= kcx) && (kcx <= gx2) && (gy1 <= kcy) && (kcy <= gy2);
    const bool m = (iou >= thr) && inside;

    const int o = task * KSEL + lane;
    out[OUT_IOUS + o] = iou;
    out[OUT_MASK + o] = m ? 1.0f : 0.0f;
    out[OUT_KIDX + o] = (float)idx;
}

// ---- Kernel 1: scatter preds into 16x16 spatial bins (per batch) ----
__global__ __launch_bounds__(THREADS) void bin_kernel(
    const float* __restrict__ pred,
    int* __restrict__ counts,       // [16][256]
    int* __restrict__ bidx,         // [16][256][BCAP]
    float2* __restrict__ bxy)       // [16][256][BCAP]
{
    const int b = blockIdx.x >> 4;                       // 16 blocks per batch
    const int t = ((blockIdx.x & 15) << 8) | threadIdx.x; // 0..4095
    const float4* p4 = reinterpret_cast<const float4*>(pred) + (size_t)b * NPRED;
    #pragma unroll
    for (int k = 0; k < 4; ++k) {
        const int i = t + k * 4096;
        const float4 p = p4[i];
        int cx = (int)(p.x * 16.0f); cx = cx < 0 ? 0 : (cx > 15 ? 15 : cx);
        int cy = (int)(p.y * 16.0f); cy = cy < 0 ? 0 : (cy > 15 ? 15 : cy);
        const int cell = (b << 8) | (cy << 4) | cx;
        const int pos = atomicAdd(&counts[cell], 1);
        if (pos < BCAP) {
            bidx[(size_t)cell * BCAP + pos] = i;
            bxy [(size_t)cell * BCAP + pos] = make_float2(p.x, p.y);
        }
    }
}

// ---- Kernel 2: per-gt selection from bins + bit-exact epilogue ----
__global__ __launch_bounds__(THREADS) void atss_select(
    const float* __restrict__ pred,
    const float* __restrict__ gt,
    const int* __restrict__ counts,
    const int* __restrict__ bidx,
    const float2* __restrict__ bxy,
    float* __restrict__ out)
{
    __shared__ u64 cand[CAP];
    __shared__ u64 topk[KSEL];
    __shared__ int s_cnt;

    const int task = blockIdx.x;          // b*128 + g
    const int b    = task >> 7;
    const int tid  = threadIdx.x;

    const float* gtp = gt + task * 4;
    const float gcx = gtp[0], gcy = gtp[1], gw = gtp[2], gh = gtp[3];
    const float* pb = pred + (size_t)b * NPRED * 4;

    float Tf = T0;
    int C = 0;
    for (int attempt = 0; attempt < 10; ++attempt) {
        if (tid == 0) s_cnt = 0;
        __syncthreads();
        const float T2 = Tf * Tf;
        // cell range covering [g - Tf, g + Tf] (floor is monotone; clamp edges)
        int x0 = (int)floorf((gcx - Tf) * 16.0f); x0 = x0 < 0 ? 0 : x0;
        int x1 = (int)floorf((gcx + Tf) * 16.0f); x1 = x1 > 15 ? 15 : x1;
        int y0 = (int)floorf((gcy - Tf) * 16.0f); y0 = y0 < 0 ? 0 : y0;
        int y1 = (int)floorf((gcy + Tf) * 16.0f); y1 = y1 > 15 ? 15 : y1;
        for (int cyy = y0; cyy <= y1; ++cyy) {
            for (int cxx = x0; cxx <= x1; ++cxx) {
                const int cell = (b << 8) | (cyy << 4) | cxx;
                int cnt = counts[cell]; cnt = cnt > BCAP ? BCAP : cnt;
                const float2* xy = bxy + (size_t)cell * BCAP;
                const int*    id = bidx + (size_t)cell * BCAP;
                for (int e = tid; e < cnt; e += THREADS) {
                    const float2 p = xy[e];
                    // Filter (ours, approximate superset); exact key inside.
                    float dx = __fsub_rn(gcx, p.x), dy = __fsub_rn(gcy, p.y);
                    if (fmaf(dx, dx, dy * dy) < T2) {
                        // numpy-exact f32 key: sqrt((dx*dx)+(dy*dy)), no FMA
                        float d = __fsqrt_rn(__fadd_rn(__fmul_rn(dx, dx),
                                                       __fmul_rn(dy, dy)));
                        int pos = atomicAdd(&s_cnt, 1);
                        if (pos < CAP)
                            cand[pos] = ((u64)__float_as_uint(d) << 32)
                                      | (unsigned)id[e];
                    }
                }
            }
        }
        __syncthreads();
        C = s_cnt;
        if (C >= KSEL && C <= CAP) break;
        __syncthreads();                    // protect s_cnt reset vs. reads
        Tf = (C < KSEL) ? Tf * 2.0f : Tf * 0.5f;
    }
    if (C > CAP) C = CAP;   // safety only

    // O(C^2) rank selection: keys unique -> ranks unique, top-64 sorted.
    for (int ci = tid; ci < C; ci += THREADS) {
        const u64 key = cand[ci];
        int r = 0;
        for (int j = 0; j < C; ++j)
            r += (cand[j] < key) ? 1 : 0;   // broadcast LDS read, conflict-free
        if (r < KSEL) topk[r] = key;
    }
    __syncthreads();

    if (tid < KSEL)
        epilogue(topk, pb, task, tid, gcx, gcy, gw, gh, out);
}

// ---- Fallback: full-scan per-gt kernel (R2 structure), used if ws too small ----
__global__ __launch_bounds__(THREADS) void atss_fullscan(
    const float* __restrict__ pred,
    const float* __restrict__ gt,
    float* __restrict__ out)
{
    __shared__ u64 cand[CAP];
    __shared__ u64 topk[KSEL];
    __shared__ int s_cnt;

    const int task = blockIdx.x;
    const int b    = task >> 7;
    const int tid  = threadIdx.x;

    const float* gtp = gt + task * 4;
    const float gcx = gtp[0], gcy = gtp[1], gw = gtp[2], gh = gtp[3];
    const float* pb = pred + (size_t)b * NPRED * 4;
    const float2* pc = reinterpret_cast<const float2*>(pb);

    float Tf = T0;
    int C = 0;
    for (int attempt = 0; attempt < 10; ++attempt) {
        if (tid == 0) s_cnt = 0;
        __syncthreads();
        const float T2 = Tf * Tf;
        #pragma unroll 8
        for (int i = tid; i < NPRED; i += THREADS) {
            const float2 p = pc[i * 2];
            float dx = __fsub_rn(gcx, p.x), dy = __fsub_rn(gcy, p.y);
            if (fmaf(dx, dx, dy * dy) < T2) {
                float d = __fsqrt_rn(__fadd_rn(__fmul_rn(dx, dx),
                                               __fmul_rn(dy, dy)));
                int pos = atomicAdd(&s_cnt, 1);
                if (pos < CAP)
                    cand[pos] = ((u64)__float_as_uint(d) << 32) | (unsigned)i;
            }
        }
        __syncthreads();
        C = s_cnt;
        if (C >= KSEL && C <= CAP) break;
        __syncthreads();
        Tf = (C < KSEL) ? Tf * 2.0f : Tf * 0.5f;
    }
    if (C > CAP) C = CAP;

    for (int ci = tid; ci < C; ci += THREADS) {
        const u64 key = cand[ci];
        int r = 0;
        for (int j = 0; j < C; ++j)
            r += (cand[j] < key) ? 1 : 0;
        if (r < KSEL) topk[r] = key;
    }
    __syncthreads();

    if (tid < KSEL)
        epilogue(topk, pb, task, tid, gcx, gcy, gw, gh, out);
}

extern "C" void kernel_launch(void* const* d_in, const int* in_sizes, int n_in,
                              void* d_out, int out_size, void* d_ws, size_t ws_size,
                              hipStream_t stream) {
    const float* pred = (const float*)d_in[0];  // (16,16384,4) f32
    const float* gtb  = (const float*)d_in[1];  // (16,128,4)   f32
    float* out = (float*)d_out;

    if (ws_size >= (size_t)WS_NEEDED) {
        char* ws = (char*)d_ws;
        int*    counts = (int*)(ws + WS_COUNTS);
        int*    bidx   = (int*)(ws + WS_BIDX);
        float2* bxy    = (float2*)(ws + WS_BXY);
        hipMemsetAsync(counts, 0, 16 * NCELL * sizeof(int), stream);
        hipLaunchKernelGGL(bin_kernel, dim3(256), dim3(THREADS), 0, stream,
                           pred, counts, bidx, bxy);
        hipLaunchKernelGGL(atss_select, dim3(16 * NGT), dim3(THREADS), 0, stream,
                           pred, gtb, counts, bidx, bxy, out);
    } else {
        hipLaunchKernelGGL(atss_fullscan, dim3(16 * NGT), dim3(THREADS), 0, stream,
                           pred, gtb, out);
    }
}

// Round 5
// 37.132 us; speedup vs baseline: 2.6253x; 1.0777x over previous
//
#include <hip/hip_runtime.h>
#include <stdint.h>

#define NPRED   16384
#define NGT     128
#define KSEL    64
#define CAP     384
#define THREADS 256
#define T0      0.055f     // initial radius (E[C] ~ 155 for uniform data)
#define BCAP    128        // per-cell capacity (mean 64, 8 sigma)
#define NCELL   256        // 16x16 grid per batch
#define MAXFC   16         // max cells handled by the flattened fast path

typedef unsigned long long u64;

// Outputs (float32, concatenated): ious[16*128*64], mask[...], k_idx[...]
#define OUT_IOUS 0
#define OUT_MASK (16 * NGT * KSEL)
#define OUT_KIDX (2 * 16 * NGT * KSEL)

// ws layout (bytes): counts[16][256], then packed bins [16][256][BCAP] float4
#define WS_COUNTS 0
#define WS_BINS   16384
#define WS_NEEDED (16384 + 16 * NCELL * BCAP * 16)

// numpy-exact pairwise sum of 64 per-lane values (n=64: 8 strided partials,
// then ((r0+r1)+(r2+r3)) + ((r4+r5)+(r6+r7))). All lanes return the sum.
// Validated bit-exact (absmax=0) in prior rounds.
__device__ __forceinline__ float npsum64(float v, int lane) {
    const int j = lane & 7;
    float r = __shfl(v, j, 64);                       // a[j]
    #pragma unroll
    for (int k = 1; k < 8; ++k)
        r = __fadd_rn(r, __shfl(v, j + 8 * k, 64));   // += a[j+8k], in order
    const float r0 = __shfl(r, 0, 64), r1 = __shfl(r, 1, 64),
                r2 = __shfl(r, 2, 64), r3 = __shfl(r, 3, 64),
                r4 = __shfl(r, 4, 64), r5 = __shfl(r, 5, 64),
                r6 = __shfl(r, 6, 64), r7 = __shfl(r, 7, 64);
    return __fadd_rn(__fadd_rn(__fadd_rn(r0, r1), __fadd_rn(r2, r3)),
                     __fadd_rn(__fadd_rn(r4, r5), __fadd_rn(r6, r7)));
}

// Shared epilogue: IoU, mean+std(ddof=1) threshold, mask — numpy-exact f32.
// Executed by lanes 0..63 of wave 0. Keys in topk[0..63].
__device__ __forceinline__ void epilogue(
    const u64* topk, const float* pb, int task, int lane,
    float gcx, float gcy, float gw, float gh, float* out)
{
    const u64 key = topk[lane];
    const int idx = (int)(key & (u64)(NPRED - 1));

    const float gx1 = __fsub_rn(gcx, __fmul_rn(0.5f, gw));
    const float gy1 = __fsub_rn(gcy, __fmul_rn(0.5f, gh));
    const float gx2 = __fadd_rn(gcx, __fmul_rn(0.5f, gw));
    const float gy2 = __fadd_rn(gcy, __fmul_rn(0.5f, gh));

    const float4 kb = *reinterpret_cast<const float4*>(pb + (size_t)idx * 4);
    const float kcx = kb.x, kcy = kb.y;
    float kx1 = __fsub_rn(kb.x, __fmul_rn(0.5f, kb.z));
    float ky1 = __fsub_rn(kb.y, __fmul_rn(0.5f, kb.w));
    float kx2 = __fadd_rn(kb.x, __fmul_rn(0.5f, kb.z));
    float ky2 = __fadd_rn(kb.y, __fmul_rn(0.5f, kb.w));
    float ltx = fmaxf(gx1, kx1), lty = fmaxf(gy1, ky1);
    float rbx = fminf(gx2, kx2), rby = fminf(gy2, ky2);
    float wx = fmaxf(__fsub_rn(rbx, ltx), 0.0f);
    float wy = fmaxf(__fsub_rn(rby, lty), 0.0f);
    float inter = __fmul_rn(wx, wy);
    float ag = __fmul_rn(__fsub_rn(gx2, gx1), __fsub_rn(gy2, gy1));
    float ak = __fmul_rn(__fsub_rn(kx2, kx1), __fsub_rn(ky2, ky1));
    float uni = __fsub_rn(__fadd_rn(ag, ak), inter);
    const float iou = __fdiv_rn(inter, uni);

    const float mean = __fdiv_rn(npsum64(iou, lane), 64.0f);
    const float dd   = __fsub_rn(iou, mean);
    const float var  = __fdiv_rn(npsum64(__fmul_rn(dd, dd), lane), 63.0f);
    const float thr  = __fadd_rn(mean, __fsqrt_rn(var));

    const bool inside = (gx1 <= kcx) && (kcx <= gx2) && (gy1 <= kcy) && (kcy <= gy2);
    const bool m = (iou >= thr) && inside;

    const int o = task * KSEL + lane;
    out[OUT_IOUS + o] = iou;
    out[OUT_MASK + o] = m ? 1.0f : 0.0f;
    out[OUT_KIDX + o] = (float)idx;
}

// ---- Kernel 0: zero the bin counters (replaces hipMemsetAsync: keeps the
// captured graph pure-compute; a graph fill node cost ~30 us/replay) ----
__global__ __launch_bounds__(THREADS) void zero_kernel(int* __restrict__ counts) {
    counts[blockIdx.x * THREADS + threadIdx.x] = 0;   // grid 16 x 256 = 4096
}

// ---- Kernel 1: scatter preds into 16x16 spatial bins (per batch) ----
// Packed entry: {cx, cy, bits(idx), 0} — one 16B store, one 16B load later.
__global__ __launch_bounds__(THREADS) void bin_kernel(
    const float* __restrict__ pred,
    int* __restrict__ counts,       // [16][256]
    float4* __restrict__ bins)      // [16][256][BCAP]
{
    const int b = blockIdx.x >> 4;                        // 16 blocks per batch
    const int t = ((blockIdx.x & 15) << 8) | threadIdx.x; // 0..4095
    const float4* p4 = reinterpret_cast<const float4*>(pred) + (size_t)b * NPRED;
    #pragma unroll
    for (int k = 0; k < 4; ++k) {
        const int i = t + k * 4096;
        const float4 p = p4[i];
        int cx = (int)(p.x * 16.0f); cx = cx < 0 ? 0 : (cx > 15 ? 15 : cx);
        int cy = (int)(p.y * 16.0f); cy = cy < 0 ? 0 : (cy > 15 ? 15 : cy);
        const int cell = (b << 8) | (cy << 4) | cx;
        const int pos = atomicAdd(&counts[cell], 1);
        if (pos < BCAP)
            bins[(size_t)cell * BCAP + pos] =
                make_float4(p.x, p.y, __int_as_float(i), 0.0f);
    }
}

// ---- Kernel 2: per-gt selection from bins + bit-exact epilogue ----
__global__ __launch_bounds__(THREADS) void atss_select(
    const float* __restrict__ pred,
    const float* __restrict__ gt,
    const int* __restrict__ counts,
    const float4* __restrict__ bins,
    float* __restrict__ out)
{
    __shared__ u64 cand[CAP];
    __shared__ u64 topk[KSEL];
    __shared__ int s_cnt;
    __shared__ int s_ccnt[MAXFC];   // per-cell counts (fast path)
    __shared__ int s_cbase[MAXFC];  // per-cell bin base offsets

    const int task = blockIdx.x;          // b*128 + g
    const int b    = task >> 7;
    const int tid  = threadIdx.x;

    const float* gtp = gt + task * 4;
    const float gcx = gtp[0], gcy = gtp[1], gw = gtp[2], gh = gtp[3];
    const float* pb = pred + (size_t)b * NPRED * 4;

    float Tf = T0;
    int C = 0;
    for (int attempt = 0; attempt < 10; ++attempt) {
        const float T2 = Tf * Tf;
        // cell range covering [g - Tf, g + Tf] (floor is monotone; clamp edges)
        int x0 = (int)floorf((gcx - Tf) * 16.0f); x0 = x0 < 0 ? 0 : x0;
        int x1 = (int)floorf((gcx + Tf) * 16.0f); x1 = x1 > 15 ? 15 : x1;
        int y0 = (int)floorf((gcy - Tf) * 16.0f); y0 = y0 < 0 ? 0 : y0;
        int y1 = (int)floorf((gcy + Tf) * 16.0f); y1 = y1 > 15 ? 15 : y1;
        const int W = x1 - x0 + 1, H = y1 - y0 + 1, NC = W * H;

        if (tid == 0) s_cnt = 0;
        if (W <= 4 && H <= 4) {
            // --- fast path: parallel count loads + flat candidate loop ---
            if (tid < MAXFC) {
                const int dx = tid & 3, dy = tid >> 2;
                int c = 0, base = 0;
                if (dx < W && dy < H) {
                    const int cell = (b << 8) | ((y0 + dy) << 4) | (x0 + dx);
                    c = counts[cell]; c = c > BCAP ? BCAP : c;
                    base = cell * BCAP;
                }
                const int q = dy * W + dx;          // valid only when in-range
                if (dx < W && dy < H) { s_ccnt[q] = c; s_cbase[q] = base; }
            }
            __syncthreads();
            // register prefix (unrolled -> static indices, stays in VGPRs)
            int ccnt[MAXFC], cbase[MAXFC], total = 0;
            #pragma unroll
            for (int q = 0; q < MAXFC; ++q) {
                const int c = (q < NC) ? s_ccnt[q] : 0;
                ccnt[q] = c; cbase[q] = (q < NC) ? s_cbase[q] : 0;
                total += c;
            }
            for (int t = tid; t < total; t += THREADS) {
                int e = t, addr = -1;
                #pragma unroll
                for (int q = 0; q < MAXFC; ++q) {
                    if (addr < 0) {
                        if (e < ccnt[q]) addr = cbase[q] + e;
                        else e -= ccnt[q];
                    }
                }
                const float4 en = bins[addr];
                float dx = __fsub_rn(gcx, en.x), dy = __fsub_rn(gcy, en.y);
                if (fmaf(dx, dx, dy * dy) < T2) {
                    // numpy-exact f32 key: sqrt((dx*dx)+(dy*dy)), no FMA
                    float d = __fsqrt_rn(__fadd_rn(__fmul_rn(dx, dx),
                                                   __fmul_rn(dy, dy)));
                    int pos = atomicAdd(&s_cnt, 1);
                    if (pos < CAP)
                        cand[pos] = ((u64)__float_as_uint(d) << 32)
                                  | (unsigned)__float_as_int(en.z);
                }
            }
        } else {
            // --- slow path (rare, after several radius doublings) ---
            __syncthreads();
            for (int cyy = y0; cyy <= y1; ++cyy) {
                for (int cxx = x0; cxx <= x1; ++cxx) {
                    const int cell = (b << 8) | (cyy << 4) | cxx;
                    int cnt = counts[cell]; cnt = cnt > BCAP ? BCAP : cnt;
                    const float4* bp = bins + (size_t)cell * BCAP;
                    for (int e = tid; e < cnt; e += THREADS) {
                        const float4 en = bp[e];
                        float dx = __fsub_rn(gcx, en.x), dy = __fsub_rn(gcy, en.y);
                        if (fmaf(dx, dx, dy * dy) < T2) {
                            float d = __fsqrt_rn(__fadd_rn(__fmul_rn(dx, dx),
                                                           __fmul_rn(dy, dy)));
                            int pos = atomicAdd(&s_cnt, 1);
                            if (pos < CAP)
                                cand[pos] = ((u64)__float_as_uint(d) << 32)
                                          | (unsigned)__float_as_int(en.z);
                        }
                    }
                }
            }
        }
        __syncthreads();
        C = s_cnt;
        if (C >= KSEL && C <= CAP) break;
        __syncthreads();                    // protect s_cnt reset vs. reads
        Tf = (C < KSEL) ? Tf * 2.0f : Tf * 0.5f;
    }
    if (C > CAP) C = CAP;   // safety only

    // O(C^2) rank selection: keys unique -> ranks unique, top-64 sorted.
    for (int ci = tid; ci < C; ci += THREADS) {
        const u64 key = cand[ci];
        int r = 0;
        for (int j = 0; j < C; ++j)
            r += (cand[j] < key) ? 1 : 0;   // broadcast LDS read, conflict-free
        if (r < KSEL) topk[r] = key;
    }
    __syncthreads();

    if (tid < KSEL)
        epilogue(topk, pb, task, tid, gcx, gcy, gw, gh, out);
}

// ---- Fallback: full-scan per-gt kernel, used only if ws too small ----
__global__ __launch_bounds__(THREADS) void atss_fullscan(
    const float* __restrict__ pred,
    const float* __restrict__ gt,
    float* __restrict__ out)
{
    __shared__ u64 cand[CAP];
    __shared__ u64 topk[KSEL];
    __shared__ int s_cnt;

    const int task = blockIdx.x;
    const int b    = task >> 7;
    const int tid  = threadIdx.x;

    const float* gtp = gt + task * 4;
    const float gcx = gtp[0], gcy = gtp[1], gw = gtp[2], gh = gtp[3];
    const float* pb = pred + (size_t)b * NPRED * 4;
    const float2* pc = reinterpret_cast<const float2*>(pb);

    float Tf = T0;
    int C = 0;
    for (int attempt = 0; attempt < 10; ++attempt) {
        if (tid == 0) s_cnt = 0;
        __syncthreads();
        const float T2 = Tf * Tf;
        #pragma unroll 8
        for (int i = tid; i < NPRED; i += THREADS) {
            const float2 p = pc[i * 2];
            float dx = __fsub_rn(gcx, p.x), dy = __fsub_rn(gcy, p.y);
            if (fmaf(dx, dx, dy * dy) < T2) {
                float d = __fsqrt_rn(__fadd_rn(__fmul_rn(dx, dx),
                                               __fmul_rn(dy, dy)));
                int pos = atomicAdd(&s_cnt, 1);
                if (pos < CAP)
                    cand[pos] = ((u64)__float_as_uint(d) << 32) | (unsigned)i;
            }
        }
        __syncthreads();
        C = s_cnt;
        if (C >= KSEL && C <= CAP) break;
        __syncthreads();
        Tf = (C < KSEL) ? Tf * 2.0f : Tf * 0.5f;
    }
    if (C > CAP) C = CAP;

    for (int ci = tid; ci < C; ci += THREADS) {
        const u64 key = cand[ci];
        int r = 0;
        for (int j = 0; j < C; ++j)
            r += (cand[j] < key) ? 1 : 0;
        if (r < KSEL) topk[r] = key;
    }
    __syncthreads();

    if (tid < KSEL)
        epilogue(topk, pb, task, tid, gcx, gcy, gw, gh, out);
}

extern "C" void kernel_launch(void* const* d_in, const int* in_sizes, int n_in,
                              void* d_out, int out_size, void* d_ws, size_t ws_size,
                              hipStream_t stream) {
    const float* pred = (const float*)d_in[0];  // (16,16384,4) f32
    const float* gtb  = (const float*)d_in[1];  // (16,128,4)   f32
    float* out = (float*)d_out;

    if (ws_size >= (size_t)WS_NEEDED) {
        char* ws = (char*)d_ws;
        int*    counts = (int*)(ws + WS_COUNTS);
        float4* bins   = (float4*)(ws + WS_BINS);
        hipLaunchKernelGGL(zero_kernel, dim3(16), dim3(THREADS), 0, stream, counts);
        hipLaunchKernelGGL(bin_kernel, dim3(256), dim3(THREADS), 0, stream,
                           pred, counts, bins);
        hipLaunchKernelGGL(atss_select, dim3(16 * NGT), dim3(THREADS), 0, stream,
                           pred, gtb, counts, bins, out);
    } else {
        hipLaunchKernelGGL(atss_fullscan, dim3(16 * NGT), dim3(THREADS), 0, stream,
                           pred, gtb, out);
    }
}